// Round 10
// baseline (803.547 us; speedup 1.0000x reference)
//
#include <hip/hip_runtime.h>
#include <math.h>

// GAT 3-layer forward. N=100000 nodes, E=1600000 edges + N self loops.
// R8 -> R9 (bugfix): R8's absmax 4.1e-2 was GCAP overflow: each bin's 256
// self-loops arrive consecutively from ONE block => one cell at mean
// 544+256=800 > 768, P(overflow)~90%/bin => ~12k dropped edges. Fix:
// self-loops never enter binning. binA bins only the 1.6M random edges
// (cell mean 511.5, sigma 22.6); binB seeds each bucket with its self-loop
// (lcnt=1, col[node*64]=node) then drains the 8 cells. GCAP 768->896
// (+17 sigma, 22.4MB scratch in bufB).
// R7 evidence (unchanged diagnosis): random 4B scatter = 102MB writes
// (line-granular amplification); binning restores write locality.

#define N_NODES 100000
#define N_EDGES 1600000
#define E_TOT   (N_EDGES + N_NODES)
#define NBINS   391            // ceil(N_NODES / 256)
#define GCAP    896            // per (group,bin) cell capacity (+17 sigma)

// ---------------- CSR build (fallback path: count + scan + fill) ----------

__global__ __launch_bounds__(256) void count_kernel(const int* __restrict__ ei,
                                                    int* __restrict__ deg) {
    int e = blockIdx.x * 256 + threadIdx.x;
    if (e >= E_TOT) return;
    int d = (e < N_EDGES) ? ei[N_EDGES + e] : (e - N_EDGES);
    atomicAdd(&deg[d], 1);
}

__global__ __launch_bounds__(1024) void scan_kernel(const int* __restrict__ deg,
                                                    int* __restrict__ row_ptr,
                                                    int* __restrict__ cursor) {
    __shared__ int wsum[16];
    const int tid = threadIdx.x;
    const int lane = tid & 63;
    const int w = tid >> 6;
    int carry = 0;
    for (int base = 0; base < N_NODES; base += 1024) {
        int i = base + tid;
        int v = (i < N_NODES) ? deg[i] : 0;
        int incl = v;
        #pragma unroll
        for (int off = 1; off < 64; off <<= 1) {
            int t = __shfl_up(incl, off);
            if (lane >= off) incl += t;
        }
        if (lane == 63) wsum[w] = incl;
        __syncthreads();
        if (w == 0) {
            int sv = (lane < 16) ? wsum[lane] : 0;
            #pragma unroll
            for (int off = 1; off < 16; off <<= 1) {
                int t = __shfl_up(sv, off);
                if (lane >= off) sv += t;
            }
            if (lane < 16) wsum[lane] = sv;
        }
        __syncthreads();
        int woff = (w > 0) ? wsum[w - 1] : 0;
        if (i < N_NODES) {
            int rp = carry + woff + incl - v;
            row_ptr[i] = rp;
            cursor[i]  = rp;
        }
        carry += wsum[15];
        __syncthreads();
    }
    if (tid == 0) row_ptr[N_NODES] = carry;
}

__global__ __launch_bounds__(256) void fill_kernel(const int* __restrict__ ei,
                                                   int* __restrict__ cursor,
                                                   int* __restrict__ col_src) {
    int e = blockIdx.x * 256 + threadIdx.x;
    if (e >= E_TOT) return;
    int s, d;
    if (e < N_EDGES) { s = ei[e]; d = ei[N_EDGES + e]; }
    else             { s = e - N_EDGES; d = s; }
    int pos = atomicAdd(&cursor[d], 1);
    col_src[pos] = s;
}

// ---------------- bucket build (fast path: two-pass binning) ---------------

// Pass A: append (s,d) into cell (group = blockIdx&7, bin = d>>8).
// RANDOM EDGES ONLY (self-loops seeded in Pass B). Sequential appends
// within a cell => L2 write-combining works.
__global__ __launch_bounds__(256) void binA_kernel(const int* __restrict__ ei,
                                                   int* __restrict__ bin_cnt,
                                                   int2* __restrict__ binbuf) {
    int t = blockIdx.x * 256 + threadIdx.x;
    int e0 = t << 2;                  // 4 edges per thread; N_EDGES % 4 == 0
    if (e0 >= N_EDGES) return;
    const int g = blockIdx.x & 7;     // ~XCD under round-robin dispatch
    int4 s4 = *(const int4*)(ei + e0);
    int4 d4 = *(const int4*)(ei + N_EDGES + e0);
    int c0 = g * NBINS + (d4.x >> 8);
    int c1 = g * NBINS + (d4.y >> 8);
    int c2 = g * NBINS + (d4.z >> 8);
    int c3 = g * NBINS + (d4.w >> 8);
    int p0 = atomicAdd(&bin_cnt[c0], 1);
    int p1 = atomicAdd(&bin_cnt[c1], 1);
    int p2 = atomicAdd(&bin_cnt[c2], 1);
    int p3 = atomicAdd(&bin_cnt[c3], 1);
    if (p0 < GCAP) binbuf[(size_t)c0 * GCAP + p0] = make_int2(s4.x, d4.x);
    if (p1 < GCAP) binbuf[(size_t)c1 * GCAP + p1] = make_int2(s4.y, d4.y);
    if (p2 < GCAP) binbuf[(size_t)c2 * GCAP + p2] = make_int2(s4.z, d4.z);
    if (p3 < GCAP) binbuf[(size_t)c3 * GCAP + p3] = make_int2(s4.w, d4.w);
}

// Pass B: one block per bin (256 nodes). Seeds each node's bucket with its
// self-loop, then drains the 8 cells. LDS per-node cursors; this block's
// col region is 64KB (single-XCD L2 resident) => coalesced writebacks.
// Also produces cnt[] (degree incl. self-loop) for edge_kernel.
__global__ __launch_bounds__(256) void binB_kernel(const int* __restrict__ bin_cnt,
                                                   const int2* __restrict__ binbuf,
                                                   int* __restrict__ cnt,
                                                   int* __restrict__ col) {
    __shared__ int lcnt[256];
    const int bi = blockIdx.x;
    const int tid = threadIdx.x;
    const int node = (bi << 8) + tid;
    if (node < N_NODES) {
        lcnt[tid] = 1;                       // self-loop seeded at slot 0
        col[(size_t)node << 6] = node;
    } else {
        lcnt[tid] = 0;
    }
    __syncthreads();
    #pragma unroll
    for (int g = 0; g < 8; ++g) {
        int cell = g * NBINS + bi;
        int n = bin_cnt[cell];
        if (n > GCAP) n = GCAP;
        const int2* cp = binbuf + (size_t)cell * GCAP;
        for (int i = tid; i < n; i += 256) {
            int2 e = cp[i];
            int pos = atomicAdd(&lcnt[e.y & 255], 1);
            if (pos < 64) col[((size_t)e.y << 6) + pos] = e.x;
        }
    }
    __syncthreads();
    if (node < N_NODES) cnt[node] = lcnt[tid];
}

// ---------------- GEMM: h = x @ W  (f32, CIN=128, COUT in {128,64}) --------

template<int CIN, int COUT>
__global__ __launch_bounds__(256) void gemm_kernel(const float* __restrict__ x,
                                                   const float* __restrict__ W,
                                                   float* __restrict__ h) {
    __shared__ float xs[32][CIN];     // 16 KB
    __shared__ float ws[64][COUT];    // 32 KB (COUT=128) / 16 KB (COUT=64)
    const int tid = threadIdx.x;
    const int row0 = blockIdx.x * 32;

    {   // stage x tile (contiguous)
        const float4* src = (const float4*)(x + (size_t)row0 * CIN);
        float4* dst = (float4*)&xs[0][0];
        #pragma unroll
        for (int i = tid; i < 32 * CIN / 4; i += 256) dst[i] = src[i];
    }

    constexpr int CG  = COUT / 4;     // col groups of 4
    constexpr int NRG = 256 / CG;     // row groups
    constexpr int RPT = 32 / NRG;     // rows per thread
    const int cg = tid % CG;
    const int rg = tid / CG;

    float4 acc[RPT];
    #pragma unroll
    for (int r = 0; r < RPT; ++r) acc[r] = make_float4(0.f, 0.f, 0.f, 0.f);

    for (int kt = 0; kt < CIN; kt += 64) {
        __syncthreads();
        {   // stage 64 rows of W (contiguous)
            const float4* src = (const float4*)(W + (size_t)kt * COUT);
            float4* dst = (float4*)&ws[0][0];
            #pragma unroll
            for (int i = tid; i < 64 * COUT / 4; i += 256) dst[i] = src[i];
        }
        __syncthreads();
        #pragma unroll 4
        for (int kk = 0; kk < 64; kk += 4) {
            float4 wv0 = *(const float4*)&ws[kk + 0][cg * 4];
            float4 wv1 = *(const float4*)&ws[kk + 1][cg * 4];
            float4 wv2 = *(const float4*)&ws[kk + 2][cg * 4];
            float4 wv3 = *(const float4*)&ws[kk + 3][cg * 4];
            #pragma unroll
            for (int r = 0; r < RPT; ++r) {
                float4 xv = *(const float4*)&xs[rg * RPT + r][kt + kk];
                acc[r].x += xv.x * wv0.x + xv.y * wv1.x + xv.z * wv2.x + xv.w * wv3.x;
                acc[r].y += xv.x * wv0.y + xv.y * wv1.y + xv.z * wv2.y + xv.w * wv3.y;
                acc[r].z += xv.x * wv0.z + xv.y * wv1.z + xv.z * wv2.z + xv.w * wv3.z;
                acc[r].w += xv.x * wv0.w + xv.y * wv1.w + xv.z * wv2.w + xv.w * wv3.w;
            }
        }
    }

    #pragma unroll
    for (int r = 0; r < RPT; ++r) {
        *(float4*)&h[(size_t)(row0 + rg * RPT + r) * COUT + cg * 4] = acc[r];
    }
}

// ---------------- per-node attention logits ----------------

template<int C>
__global__ __launch_bounds__(256) void al_kernel(const float* __restrict__ h,
                                                 const float* __restrict__ a_src,
                                                 const float* __restrict__ a_dst,
                                                 float* __restrict__ al_s,
                                                 float* __restrict__ al_d) {
    int wid = (blockIdx.x * 256 + threadIdx.x) >> 6;
    int lane = threadIdx.x & 63;
    if (wid >= N_NODES) return;
    const float* row = h + (size_t)wid * C;
    float s = 0.f, d = 0.f;
    #pragma unroll
    for (int c = lane; c < C; c += 64) {
        float v = row[c];
        s += v * a_src[c];
        d += v * a_dst[c];
    }
    #pragma unroll
    for (int off = 32; off; off >>= 1) {
        s += __shfl_down(s, off);
        d += __shfl_down(d, off);
    }
    if (lane == 0) { al_s[wid] = s; al_d[wid] = d; }
}

// ---------------- edge softmax + aggregation (one wave per dst node) -------

__device__ __forceinline__ float lrelu02(float e) {
    return (e >= 0.f) ? e : 0.2f * e;
}

// FIXED: rp = cnt[], col = fixed 64-slot buckets, beg = wid*64.
// !FIXED: rp = row_ptr[], col = CSR col_src.
template<int C, bool RELU, bool FIXED>
__global__ __launch_bounds__(256) void edge_kernel(const int* __restrict__ rp,
                                                   const int* __restrict__ col,
                                                   const float* __restrict__ al_s,
                                                   const float* __restrict__ al_d,
                                                   const float* __restrict__ h,
                                                   const float* __restrict__ b,
                                                   float* __restrict__ out) {
    __shared__ float2 ed[4][64];      // per-wave {alpha, src-bits} stash
    int wid = (blockIdx.x * 256 + threadIdx.x) >> 6;
    int lane = threadIdx.x & 63;
    int wrp = (threadIdx.x >> 6) & 3;
    if (wid >= N_NODES) return;
    int beg, deg;
    if (FIXED) {
        beg = wid << 6;
        deg = rp[wid];
        if (deg > 64) deg = 64;       // astronomically unlikely; OOB guard
    } else {
        beg = rp[wid];
        deg = rp[wid + 1] - beg;
    }
    const int end = beg + deg;
    const float ald = al_d[wid];

    // phase 1: per-lane online (max, sum-of-exp); lane L owns edges L, L+64,...
    float m = -1e30f, ssum = 0.f;
    int   s_first = 0;
    float e_first = 0.f;
    {
        int j = beg + lane;
        if (j < end) {
            s_first = col[j];
            e_first = lrelu02(al_s[s_first] + ald);
            m = e_first; ssum = 1.f;
            for (j += 64; j < end; j += 64) {   // no-op when deg <= 64
                int s = col[j];
                float e = lrelu02(al_s[s] + ald);
                float M = fmaxf(m, e);
                ssum = ssum * __expf(m - M) + __expf(e - M);
                m = M;
            }
        }
    }
    // butterfly merge across 64 lanes -> wave-uniform m, ssum
    #pragma unroll
    for (int off = 1; off < 64; off <<= 1) {
        float m2 = __shfl_xor(m, off);
        float s2 = __shfl_xor(ssum, off);
        float M = fmaxf(m, m2);
        ssum = ssum * __expf(m - M) + s2 * __expf(m2 - M);
        m = M;
    }
    const float inv = 1.f / ssum;

    // stash this lane's (alpha, src) for wave-wide broadcast (same-wave
    // LDS RAW needs only lgkmcnt, no barrier)
    ed[wrp][lane] = make_float2(__expf(e_first - m), __int_as_float(s_first));

    // phase 2: per edge t: one uniform ds_read_b64 -> gather h row
    const int nfast = (deg < 64) ? deg : 64;
    if (C == 128) {
        const float2* hb = (const float2*)h;
        float ax = 0.f, ay = 0.f;
        int t = 0;
        for (; t + 8 <= nfast; t += 8) {
            #pragma unroll
            for (int k = 0; k < 8; ++k) {
                float2 p = ed[wrp][t + k];
                int s = __float_as_int(p.y);
                float2 v = hb[((size_t)s << 6) + lane];
                ax += p.x * v.x; ay += p.x * v.y;
            }
        }
        for (; t < nfast; ++t) {
            float2 p = ed[wrp][t];
            int s = __float_as_int(p.y);
            float2 v = hb[((size_t)s << 6) + lane];
            ax += p.x * v.x; ay += p.x * v.y;
        }
        for (; t < deg; ++t) {            // deg > 64 CSR fallback only
            int s = col[beg + t];
            float w = __expf(lrelu02(al_s[s] + ald) - m);
            float2 v = hb[((size_t)s << 6) + lane];
            ax += w * v.x; ay += w * v.y;
        }
        float2 bb = ((const float2*)b)[lane];
        float ox = ax * inv + bb.x;
        float oy = ay * inv + bb.y;
        if (RELU) { ox = fmaxf(ox, 0.f); oy = fmaxf(oy, 0.f); }
        *((float2*)(out + (size_t)wid * C) + lane) = make_float2(ox, oy);
    } else {
        // C == 64: lane covers channel `lane`
        float a0 = 0.f;
        int t = 0;
        for (; t + 8 <= nfast; t += 8) {
            #pragma unroll
            for (int k = 0; k < 8; ++k) {
                float2 p = ed[wrp][t + k];
                int s = __float_as_int(p.y);
                a0 += p.x * h[((size_t)s << 6) + lane];
            }
        }
        for (; t < nfast; ++t) {
            float2 p = ed[wrp][t];
            int s = __float_as_int(p.y);
            a0 += p.x * h[((size_t)s << 6) + lane];
        }
        for (; t < deg; ++t) {
            int s = col[beg + t];
            float w = __expf(lrelu02(al_s[s] + ald) - m);
            a0 += w * h[((size_t)s << 6) + lane];
        }
        float o0 = a0 * inv + b[lane];
        if (RELU) o0 = fmaxf(o0, 0.f);
        out[(size_t)wid * C + lane] = o0;
    }
}

// ---------------- launch ----------------

extern "C" void kernel_launch(void* const* d_in, const int* in_sizes, int n_in,
                              void* d_out, int out_size, void* d_ws, size_t ws_size,
                              hipStream_t stream) {
    const float* x   = (const float*)d_in[0];
    const int*   ei  = (const int*)d_in[1];
    const float* W1  = (const float*)d_in[2];
    const float* as1 = (const float*)d_in[3];
    const float* ad1 = (const float*)d_in[4];
    const float* b1  = (const float*)d_in[5];
    const float* W2  = (const float*)d_in[6];
    const float* as2 = (const float*)d_in[7];
    const float* ad2 = (const float*)d_in[8];
    const float* b2  = (const float*)d_in[9];
    const float* W3  = (const float*)d_in[10];
    const float* as3 = (const float*)d_in[11];
    const float* ad3 = (const float*)d_in[12];
    const float* b3  = (const float*)d_in[13];
    float* out = (float*)d_out;

    char* wsb = (char*)d_ws;
    const int gb = N_NODES / 32;              // 3125 (exact)
    const int vb = (N_NODES * 64 + 255) / 256;// 25000 (one wave per node)

    // ---- fast layout: fixed 64-slot buckets (~129.2 MB, same as R7) ----
    size_t off = 0;
    auto alloc = [&](size_t bytes) -> char* {
        char* p = wsb + off;
        off = (off + bytes + 255) & ~(size_t)255;
        return p;
    };
    int*   cnt  = (int*)  alloc((size_t)N_NODES * 4);
    int*   colf = (int*)  alloc((size_t)N_NODES * 64 * 4);
    float* al_s = (float*)alloc((size_t)N_NODES * 4);
    float* al_d = (float*)alloc((size_t)N_NODES * 4);
    float* bufA = (float*)alloc((size_t)N_NODES * 128 * 4);
    float* bufB = (float*)alloc((size_t)N_NODES * 128 * 4);

    if (off <= ws_size) {
        // ---- fast path: two-pass binned bucket build ----
        // scratch carved from buffers written later in the stream:
        int*  bin_cnt = (int*)bufA;           // 8*NBINS*4 = 12.5 KB << 51.2 MB
        int2* binbuf  = (int2*)bufB;          // 8*NBINS*GCAP*8 = 22.4 MB << 51.2 MB

        hipMemsetAsync(bin_cnt, 0, (size_t)8 * NBINS * 4, stream);
        const int ab = (N_EDGES / 4 + 255) / 256;   // 1563
        binA_kernel<<<ab, 256, 0, stream>>>(ei, bin_cnt, binbuf);
        binB_kernel<<<NBINS, 256, 0, stream>>>(bin_cnt, binbuf, cnt, colf);

        gemm_kernel<128, 128><<<gb, 256, 0, stream>>>(x, W1, bufB);
        al_kernel<128><<<vb, 256, 0, stream>>>(bufB, as1, ad1, al_s, al_d);
        edge_kernel<128, true, true><<<vb, 256, 0, stream>>>(cnt, colf, al_s, al_d, bufB, b1, bufA);

        gemm_kernel<128, 128><<<gb, 256, 0, stream>>>(bufA, W2, bufB);
        al_kernel<128><<<vb, 256, 0, stream>>>(bufB, as2, ad2, al_s, al_d);
        edge_kernel<128, true, true><<<vb, 256, 0, stream>>>(cnt, colf, al_s, al_d, bufB, b2, bufA);

        gemm_kernel<128, 64><<<gb, 256, 0, stream>>>(bufA, W3, bufB);
        al_kernel<64><<<vb, 256, 0, stream>>>(bufB, as3, ad3, al_s, al_d);
        edge_kernel<64, false, true><<<vb, 256, 0, stream>>>(cnt, colf, al_s, al_d, bufB, b3, out);
    } else {
        // ---- fallback: R6 pipeline (dynamic CSR), ~110.8 MB ----
        size_t o2 = 0;
        auto alloc2 = [&](size_t bytes) -> char* {
            char* p = wsb + o2;
            o2 = (o2 + bytes + 255) & ~(size_t)255;
            return p;
        };
        int*   row_ptr = (int*)  alloc2((size_t)(N_NODES + 1) * 4);
        int*   cursor  = (int*)  alloc2((size_t)N_NODES * 4);
        int*   col_src = (int*)  alloc2((size_t)E_TOT * 4);
        float* al_s2   = (float*)alloc2((size_t)N_NODES * 4);
        float* al_d2   = (float*)alloc2((size_t)N_NODES * 4);
        float* bufA2   = (float*)alloc2((size_t)N_NODES * 128 * 4);
        float* bufB2   = (float*)alloc2((size_t)N_NODES * 128 * 4);

        const int eb = (E_TOT + 255) / 256;
        hipMemsetAsync(cursor, 0, (size_t)N_NODES * 4, stream);
        count_kernel<<<eb, 256, 0, stream>>>(ei, cursor);
        scan_kernel<<<1, 1024, 0, stream>>>(cursor, row_ptr, cursor);
        fill_kernel<<<eb, 256, 0, stream>>>(ei, cursor, col_src);

        gemm_kernel<128, 128><<<gb, 256, 0, stream>>>(x, W1, bufB2);
        al_kernel<128><<<vb, 256, 0, stream>>>(bufB2, as1, ad1, al_s2, al_d2);
        edge_kernel<128, true, false><<<vb, 256, 0, stream>>>(row_ptr, col_src, al_s2, al_d2, bufB2, b1, bufA2);

        gemm_kernel<128, 128><<<gb, 256, 0, stream>>>(bufA2, W2, bufB2);
        al_kernel<128><<<vb, 256, 0, stream>>>(bufB2, as2, ad2, al_s2, al_d2);
        edge_kernel<128, true, false><<<vb, 256, 0, stream>>>(row_ptr, col_src, al_s2, al_d2, bufB2, b2, bufA2);

        gemm_kernel<128, 64><<<gb, 256, 0, stream>>>(bufA2, W3, bufB2);
        al_kernel<64><<<vb, 256, 0, stream>>>(bufB2, as3, ad3, al_s2, al_d2);
        edge_kernel<64, false, false><<<vb, 256, 0, stream>>>(row_ptr, col_src, al_s2, al_d2, bufB2, b3, out);
    }
}